// Round 5
// baseline (946.021 us; speedup 1.0000x reference)
//
#include <hip/hip_runtime.h>
#include <math.h>

#define TOK   1024
#define HSZ   1024
#define DIM   128
#define NWRDC 32000
#define NTGTC 2000

typedef __attribute__((ext_vector_type(8))) short bf16x8;
typedef __attribute__((ext_vector_type(4))) float f32x4;

__device__ __forceinline__ ushort f2bf(float x) {
    union { float f; uint u; } c; c.f = x;
    return (ushort)((c.u + 0x7fffu + ((c.u >> 16) & 1u)) >> 16);
}
__device__ __forceinline__ float bf2f(ushort h) {
    union { uint u; float f; } c; c.u = ((uint)h) << 16;
    return c.f;
}
__device__ __forceinline__ uint4 pk8(const ushort v[8]) {
    uint4 u;
    u.x = (uint)v[0] | ((uint)v[1] << 16);
    u.y = (uint)v[2] | ((uint)v[3] << 16);
    u.z = (uint)v[4] | ((uint)v[5] << 16);
    u.w = (uint)v[6] | ((uint)v[7] << 16);
    return u;
}

#define GLL16(SRC, DST) __builtin_amdgcn_global_load_lds( \
    (const __attribute__((address_space(1))) void*)(SRC), \
    (__attribute__((address_space(3))) void*)(DST), 16, 0, 0)

// ---------------------------------------------------------------------------
__global__ __launch_bounds__(256) void split_ctx3(
    const float* __restrict__ x, ushort* __restrict__ hp,
    ushort* __restrict__ mp, ushort* __restrict__ lp)
{
    const int i4 = (blockIdx.x * 256 + threadIdx.x) * 4;
    float4 v = *(const float4*)(x + i4);
    float xs[4] = {v.x, v.y, v.z, v.w};
    ushort hh[4], mm[4], ll[4];
    #pragma unroll
    for (int k = 0; k < 4; ++k) {
        ushort h = f2bf(xs[k]);
        float r1 = xs[k] - bf2f(h);
        ushort m = f2bf(r1);
        ushort l = f2bf(r1 - bf2f(m));
        hh[k] = h; mm[k] = m; ll[k] = l;
    }
    uint2 u;
    u.x = (uint)hh[0] | ((uint)hh[1] << 16); u.y = (uint)hh[2] | ((uint)hh[3] << 16);
    *(uint2*)(hp + i4) = u;
    u.x = (uint)mm[0] | ((uint)mm[1] << 16); u.y = (uint)mm[2] | ((uint)mm[3] << 16);
    *(uint2*)(mp + i4) = u;
    u.x = (uint)ll[0] | ((uint)ll[1] << 16); u.y = (uint)ll[2] | ((uint)ll[3] << 16);
    *(uint2*)(lp + i4) = u;
}

// ---------------------------------------------------------------------------
// head body. Single barrier per K-step; A via gll (dbuf); W f32->bf16 in-loop
// (trunc-hi) with conflict-free b64 writes (dbuf B).
// LDS: A0h@0 A0l@8192 A1h@16384 A1l@24576 B0h@32768 B0l@40960 B1h@49152
// B1l@57344; epilogue alias P@0, EM@34816; stats @65536/66560/67584.
// element (row,k): pair=row>>1, ch=(((row&1)<<2)|(k>>3))^(pair&7)^((pair>>3)&3)
//   byte = pair*128 + ch*16 + (k&7)*2
// ---------------------------------------------------------------------------
__device__ __forceinline__ void head_body(
    char* smem, int b, int NVx,
    const ushort* __restrict__ ctx_hi, const ushort* __restrict__ ctx_lo,
    const float* __restrict__ W, const float* __restrict__ bias,
    const float* __restrict__ g, const float* __restrict__ emb,
    int V, int ldg, int tps, int n_tiles,
    float* __restrict__ wsW, float* __restrict__ wsBV,
    int* __restrict__ wsBI, float* __restrict__ wsE)
{
    ushort* Pl = (ushort*)smem;
    ushort* EM = (ushort*)(smem + 34816);
    float* sm_wsum = (float*)(smem + 65536);
    float* sm_bval = (float*)(smem + 66560);
    int*   sm_bidx = (int*)(smem + 67584);

    const int tid  = threadIdx.x;
    const int lane = tid & 63;
    const int fr   = lane & 15;
    const int fg   = lane >> 4;
    const int wv   = tid >> 6;
    const int wrow = wv >> 1;
    const int wcol = wv & 1;
    const int split = b % NVx;
    const int t0    = (b / NVx) * 128;

    if (tid < 128) {
        sm_wsum[tid * 2] = 0.f;        sm_wsum[tid * 2 + 1] = 0.f;
        sm_bval[tid * 2] = -INFINITY;  sm_bval[tid * 2 + 1] = -INFINITY;
        sm_bidx[tid * 2] = 0;          sm_bidx[tid * 2 + 1] = 0;
    }

    const int chunkRd0 = (((fr & 1) << 2) | fg) ^ ((fr >> 1) & 7);
    int aRd[4], bRd[4];
    #pragma unroll
    for (int i = 0; i < 4; ++i) {
        aRd[i] = wrow * 4096 + i * 1024 + (fr >> 1) * 128 + ((chunkRd0 ^ i) << 4);
        bRd[i] = wcol * 4096 + i * 1024 + (fr >> 1) * 128 + ((chunkRd0 ^ i) << 4);
    }

    const int v_    = (lane & 7) ^ (lane >> 3) ^ (wv & 3);
    const int glTok = (wv * 8 + (lane >> 3)) * 2 + (v_ >> 2);
    const int glK   = (v_ & 3) * 8;
    const int glDst = wv * 1024;

    const int c4 = (tid & 31) * 4;
    const int hq = tid >> 5;
    const int kc_w = hq >> 1, half_w = hq & 1;
    int wOff[4];
    #pragma unroll
    for (int i = 0; i < 4; ++i) {
        const int col = c4 + i;
        const int pair = col >> 1;
        const int ch = (((col & 1) << 2) | kc_w) ^ (pair & 7) ^ ((pair >> 3) & 3);
        wOff[i] = pair * 128 + ch * 16 + half_w * 8;
    }

    f32x4 zero4 = {0.f, 0.f, 0.f, 0.f};
    f32x4 Eacc[4][4];
    #pragma unroll
    for (int i = 0; i < 4; ++i)
        #pragma unroll
        for (int j = 0; j < 4; ++j) Eacc[i][j] = zero4;

    int tbeg = split * tps;
    int tend = tbeg + tps; if (tend > n_tiles) tend = n_tiles;

    #define STAGE_A(STEP, BASE) do {                                               \
        const size_t ro_ = (size_t)(t0 + glTok) * HSZ + (size_t)(STEP) * 32 + glK; \
        GLL16(ctx_hi + ro_,          (BASE) + glDst);                              \
        GLL16(ctx_hi + ro_ + 65536,  (BASE) + 4096 + glDst);                       \
        GLL16(ctx_lo + ro_,          (BASE) + 8192 + glDst);                       \
        GLL16(ctx_lo + ro_ + 65536,  (BASE) + 12288 + glDst);                      \
    } while (0)

    #define LOAD_W(STEP, VV) do {                                                 \
        const int gc_ = c0 + c4;                                                   \
        if (gc_ < V) {                                                             \
            const float* p_ = W + (size_t)((STEP) * 32 + hq * 4) * V + gc_;        \
            VV[0] = *(const float4*)p_;                                            \
            VV[1] = *(const float4*)(p_ + V);                                      \
            VV[2] = *(const float4*)(p_ + 2 * (size_t)V);                          \
            VV[3] = *(const float4*)(p_ + 3 * (size_t)V);                          \
        } else {                                                                   \
            float4 z_ = {0.f, 0.f, 0.f, 0.f};                                      \
            VV[0] = z_; VV[1] = z_; VV[2] = z_; VV[3] = z_;                        \
        }                                                                          \
    } while (0)

    #define CONV_W(BH, BL, VV) do {                                               \
        _Pragma("unroll")                                                          \
        for (int i_ = 0; i_ < 4; ++i_) {                                           \
            ushort h_[4], l_[4];                                                   \
            _Pragma("unroll")                                                      \
            for (int q_ = 0; q_ < 4; ++q_) {                                       \
                float x_ = ((const float*)&VV[q_])[i_];                            \
                union { float f; uint u; } c_; c_.f = x_;                          \
                h_[q_] = (ushort)(c_.u >> 16);                                     \
                union { uint u; float f; } t_; t_.u = c_.u & 0xFFFF0000u;          \
                l_[q_] = f2bf(x_ - t_.f);                                          \
            }                                                                      \
            uint2 uh_ = {(uint)h_[0] | ((uint)h_[1] << 16),                        \
                         (uint)h_[2] | ((uint)h_[3] << 16)};                       \
            uint2 ul_ = {(uint)l_[0] | ((uint)l_[1] << 16),                        \
                         (uint)l_[2] | ((uint)l_[3] << 16)};                       \
            *(uint2*)((BH) + wOff[i_]) = uh_;                                      \
            *(uint2*)((BL) + wOff[i_]) = ul_;                                      \
        }                                                                          \
    } while (0)

    for (int tt = tbeg; tt < tend; ++tt) {
        const int c0 = tt * 128;
        f32x4 acc[4][4];
        #pragma unroll
        for (int i = 0; i < 4; ++i)
            #pragma unroll
            for (int j = 0; j < 4; ++j) acc[i][j] = zero4;

        STAGE_A(0, smem);
        {
            float4 v0[4];
            LOAD_W(0, v0);
            CONV_W(smem + 32768, smem + 40960, v0);
        }
        __syncthreads();

        for (int ks = 0; ks < 32; ++ks) {
            const int cur = ks & 1;
            const bool more = (ks + 1) < 32;
            float4 vn[4];
            if (more) {
                STAGE_A(ks + 1, smem + (cur ^ 1) * 16384);
                LOAD_W(ks + 1, vn);
            }
            char* bA = smem + cur * 16384;
            char* bB = smem + 32768 + cur * 16384;
            bf16x8 ah[4], al[4];
            #pragma unroll
            for (int i = 0; i < 4; ++i) {
                ah[i] = *(const bf16x8*)(bA + aRd[i]);
                al[i] = *(const bf16x8*)(bA + 8192 + aRd[i]);
            }
            __builtin_amdgcn_s_setprio(1);
            #pragma unroll
            for (int j = 0; j < 4; ++j) {
                bf16x8 vbh = *(const bf16x8*)(bB + bRd[j]);
                bf16x8 vbl = *(const bf16x8*)(bB + 8192 + bRd[j]);
                #pragma unroll
                for (int i = 0; i < 4; ++i) {
                    acc[i][j] = __builtin_amdgcn_mfma_f32_16x16x32_bf16(ah[i], vbh, acc[i][j], 0, 0, 0);
                    acc[i][j] = __builtin_amdgcn_mfma_f32_16x16x32_bf16(ah[i], vbl, acc[i][j], 0, 0, 0);
                    acc[i][j] = __builtin_amdgcn_mfma_f32_16x16x32_bf16(al[i], vbh, acc[i][j], 0, 0, 0);
                }
            }
            __builtin_amdgcn_s_setprio(0);
            if (more) {
                char* nB = smem + 32768 + (cur ^ 1) * 16384;
                CONV_W(nB, nB + 8192, vn);
            }
            __syncthreads();
        }

        float bias4[4];
        #pragma unroll
        for (int j = 0; j < 4; ++j) {
            const int gc = c0 + wcol * 64 + j * 16 + fr;
            bias4[j] = (gc < V) ? bias[gc] : 0.f;
        }
        #pragma unroll
        for (int i = 0; i < 4; ++i) {
            #pragma unroll
            for (int r = 0; r < 4; ++r) {
                const int trow = wrow * 64 + i * 16 + fg * 4 + r;
                const float* gp = g + (size_t)(t0 + trow) * ldg + c0 + wcol * 64 + fr;
                float esum = 0.f, mx = -INFINITY;
                int mi = 0;
                #pragma unroll
                for (int j = 0; j < 4; ++j) {
                    const int gc = c0 + wcol * 64 + j * 16 + fr;
                    float e = 0.f;
                    if (gc < V) {
                        const float s = acc[i][j][r] + bias4[j] + gp[j * 16];
                        e = __expf(s);
                        esum += e;
                        if (s > mx) { mx = s; mi = gc; }
                    }
                    Pl[trow * 136 + wcol * 64 + j * 16 + fr] = f2bf(e);
                }
                #pragma unroll
                for (int off = 1; off < 16; off <<= 1) {
                    const float ov = __shfl_xor(mx, off, 64);
                    const int   oi = __shfl_xor(mi, off, 64);
                    esum += __shfl_xor(esum, off, 64);
                    if (ov > mx || (ov == mx && oi < mi)) { mx = ov; mi = oi; }
                }
                if (fr == 0) {
                    sm_wsum[trow * 2 + wcol] += esum;
                    const float cb = sm_bval[trow * 2 + wcol];
                    const int   ci = sm_bidx[trow * 2 + wcol];
                    if (mx > cb || (mx == cb && mi < ci)) {
                        sm_bval[trow * 2 + wcol] = mx;
                        sm_bidx[trow * 2 + wcol] = mi;
                    }
                }
            }
        }

        #pragma unroll
        for (int hf = 0; hf < 2; ++hf) {
            __syncthreads();
            #pragma unroll
            for (int rr = 0; rr < 4; ++rr) {
                const int task = tid + rr * 256;
                const int d = task & 127;
                const int cc = task >> 7;
                ushort o8[8];
                #pragma unroll
                for (int j = 0; j < 8; ++j) {
                    const int gc = c0 + hf * 64 + cc * 8 + j;
                    o8[j] = (gc < V) ? f2bf(emb[(size_t)gc * DIM + d]) : (ushort)0;
                }
                *(uint4*)(EM + d * 72 + cc * 8) = pk8(o8);
            }
            __syncthreads();
            #pragma unroll
            for (int ksb = 0; ksb < 2; ++ksb) {
                bf16x8 ap[4];
                #pragma unroll
                for (int i = 0; i < 4; ++i) {
                    const int row = wrow * 64 + i * 16 + fr;
                    ap[i] = *(const bf16x8*)(Pl + row * 136 + hf * 64 + ksb * 32 + fg * 8);
                }
                #pragma unroll
                for (int j = 0; j < 4; ++j) {
                    const int dd = wcol * 64 + j * 16 + fr;
                    bf16x8 eb = *(const bf16x8*)(EM + dd * 72 + ksb * 32 + fg * 8);
                    #pragma unroll
                    for (int i = 0; i < 4; ++i)
                        Eacc[i][j] = __builtin_amdgcn_mfma_f32_16x16x32_bf16(ap[i], eb, Eacc[i][j], 0, 0, 0);
                }
            }
        }
        __syncthreads();
    }

    __syncthreads();
    if (tid < 128) {
        const float wsv = sm_wsum[tid * 2] + sm_wsum[tid * 2 + 1];
        const float b0 = sm_bval[tid * 2], b1 = sm_bval[tid * 2 + 1];
        const int   i0 = sm_bidx[tid * 2], i1 = sm_bidx[tid * 2 + 1];
        float bv; int bi;
        if (b0 > b1 || (b0 == b1 && i0 < i1)) { bv = b0; bi = i0; }
        else                                   { bv = b1; bi = i1; }
        const size_t o = (size_t)split * TOK + t0 + tid;
        wsW[o] = wsv; wsBV[o] = bv; wsBI[o] = bi;
    }
    #pragma unroll
    for (int i = 0; i < 4; ++i)
        #pragma unroll
        for (int j = 0; j < 4; ++j)
            #pragma unroll
            for (int r = 0; r < 4; ++r) {
                const int trow = wrow * 64 + i * 16 + fg * 4 + r;
                const int dd   = wcol * 64 + j * 16 + fr;
                wsE[((size_t)split * TOK + t0 + trow) * DIM + dd] = Eacc[i][j][r];
            }
    #undef STAGE_A
    #undef LOAD_W
    #undef CONV_W
}

// ---------------------------------------------------------------------------
__device__ __forceinline__ void cpy_body(
    char* smemc, int cb,
    const ushort* __restrict__ ahi, const ushort* __restrict__ amd,
    const ushort* __restrict__ alo, const float* __restrict__ Wc,
    const float* __restrict__ ctx, const float* __restrict__ bc,
    float* __restrict__ pcpyP)
{
    ushort* sm = (ushort*)smemc;
    ushort* Ah = sm;
    ushort* Am = sm + 5120;
    ushort* Al = sm + 10240;
    ushort* Bh = sm + 15360;
    ushort* Bm = sm + 20480;
    ushort* Bl = sm + 25600;

    const int tid  = threadIdx.x;
    const int lane = tid & 63;
    const int fr   = lane & 15;
    const int fg   = lane >> 4;
    const int w    = tid >> 6;
    const int wrow = w >> 1;
    const int wcol = w & 1;
    const int t0   = (cb >> 3) * 128;
    const int c0   = (cb & 7) * 128;

    const int arow = tid >> 2, akc = tid & 3;
    const int bcol = tid & 127, bkc0 = tid >> 7;

    f32x4 zero4 = {0.f, 0.f, 0.f, 0.f};
    f32x4 acc[4][4];
    #pragma unroll
    for (int i = 0; i < 4; ++i)
        #pragma unroll
        for (int j = 0; j < 4; ++j) acc[i][j] = zero4;

    for (int h0 = 0; h0 < HSZ; h0 += 32) {
        uint4 aH[2], aM[2], aL[2];
        float bx[2][8];
        #pragma unroll
        for (int rr = 0; rr < 2; ++rr) {
            const size_t so = (size_t)(t0 + arow + rr * 64) * HSZ + h0 + akc * 8;
            aH[rr] = *(const uint4*)(ahi + so);
            aM[rr] = *(const uint4*)(amd + so);
            aL[rr] = *(const uint4*)(alo + so);
        }
        #pragma unroll
        for (int rr = 0; rr < 2; ++rr) {
            const int kc = bkc0 + rr * 2;
            const float* wp = Wc + (size_t)(h0 + kc * 8) * HSZ + c0 + bcol;
            #pragma unroll
            for (int j = 0; j < 8; ++j) bx[rr][j] = wp[(size_t)j * HSZ];
        }
        __syncthreads();
        #pragma unroll
        for (int rr = 0; rr < 2; ++rr) {
            const int row = arow + rr * 64;
            *(uint4*)(Ah + row * 40 + akc * 8) = aH[rr];
            *(uint4*)(Am + row * 40 + akc * 8) = aM[rr];
            *(uint4*)(Al + row * 40 + akc * 8) = aL[rr];
        }
        #pragma unroll
        for (int rr = 0; rr < 2; ++rr) {
            const int kc = bkc0 + rr * 2;
            ushort hh[8], mm[8], ll[8];
            #pragma unroll
            for (int j = 0; j < 8; ++j) {
                float x = bx[rr][j];
                ushort h = f2bf(x);
                float r1 = x - bf2f(h);
                ushort m = f2bf(r1);
                hh[j] = h; mm[j] = m; ll[j] = f2bf(r1 - bf2f(m));
            }
            *(uint4*)(Bh + bcol * 40 + kc * 8) = pk8(hh);
            *(uint4*)(Bm + bcol * 40 + kc * 8) = pk8(mm);
            *(uint4*)(Bl + bcol * 40 + kc * 8) = pk8(ll);
        }
        __syncthreads();
        bf16x8 a1[4], a2[4], a3[4];
        #pragma unroll
        for (int i = 0; i < 4; ++i) {
            const int row = wrow * 64 + i * 16 + fr;
            a1[i] = *(const bf16x8*)(Ah + row * 40 + fg * 8);
            a2[i] = *(const bf16x8*)(Am + row * 40 + fg * 8);
            a3[i] = *(const bf16x8*)(Al + row * 40 + fg * 8);
        }
        #pragma unroll
        for (int j = 0; j < 4; ++j) {
            const int cr = wcol * 64 + j * 16 + fr;
            bf16x8 b1 = *(const bf16x8*)(Bh + cr * 40 + fg * 8);
            bf16x8 b2 = *(const bf16x8*)(Bm + cr * 40 + fg * 8);
            bf16x8 b3 = *(const bf16x8*)(Bl + cr * 40 + fg * 8);
            #pragma unroll
            for (int i = 0; i < 4; ++i) {
                acc[i][j] = __builtin_amdgcn_mfma_f32_16x16x32_bf16(a1[i], b1, acc[i][j], 0, 0, 0);
                acc[i][j] = __builtin_amdgcn_mfma_f32_16x16x32_bf16(a1[i], b2, acc[i][j], 0, 0, 0);
                acc[i][j] = __builtin_amdgcn_mfma_f32_16x16x32_bf16(a2[i], b1, acc[i][j], 0, 0, 0);
                acc[i][j] = __builtin_amdgcn_mfma_f32_16x16x32_bf16(a1[i], b3, acc[i][j], 0, 0, 0);
                acc[i][j] = __builtin_amdgcn_mfma_f32_16x16x32_bf16(a3[i], b1, acc[i][j], 0, 0, 0);
                acc[i][j] = __builtin_amdgcn_mfma_f32_16x16x32_bf16(a2[i], b2, acc[i][j], 0, 0, 0);
            }
        }
    }

    __syncthreads();
    float* red = (float*)smemc;
    float bb[4];
    #pragma unroll
    for (int j = 0; j < 4; ++j) bb[j] = bc[c0 + wcol * 64 + j * 16 + fr];
    #pragma unroll
    for (int i = 0; i < 4; ++i) {
        #pragma unroll
        for (int r = 0; r < 4; ++r) {
            const int trow = wrow * 64 + i * 16 + fg * 4 + r;
            const float* cx = ctx + (size_t)(t0 + trow) * HSZ + c0;
            float s = 0.f;
            #pragma unroll
            for (int j = 0; j < 4; ++j) {
                const int dd = wcol * 64 + j * 16 + fr;
                s += (acc[i][j][r] + bb[j]) * cx[dd];
            }
            #pragma unroll
            for (int off = 1; off < 16; off <<= 1) s += __shfl_xor(s, off, 64);
            if (fr == 0) red[trow * 2 + wcol] = s;
        }
    }
    __syncthreads();
    if (tid < 128)
        pcpyP[(size_t)(cb & 7) * TOK + t0 + tid] = red[tid * 2] + red[tid * 2 + 1];
}

// ---------------------------------------------------------------------------
__global__ __launch_bounds__(256, 2) void mega_kernel(
    const ushort* __restrict__ ctxh, const ushort* __restrict__ ctxm,
    const ushort* __restrict__ ctxl,
    const float* __restrict__ W_nrm, const float* __restrict__ b_nrm,
    const float* __restrict__ g_nrm, const float* __restrict__ word_emb,
    const float* __restrict__ W_spt, const float* __restrict__ b_spt,
    const float* __restrict__ g_spt, const float* __restrict__ word_emb_tgt,
    const float* __restrict__ W_cpy, const float* __restrict__ b_cpy,
    const float* __restrict__ ctx, float* __restrict__ pcpyP,
    int NVn, int tps_n, int NVs, int tps_s,
    float* __restrict__ nW, float* __restrict__ nBV, int* __restrict__ nBI,
    float* __restrict__ nE,
    float* __restrict__ sW, float* __restrict__ sBV, int* __restrict__ sBI,
    float* __restrict__ sE)
{
    __shared__ __align__(16) char smem[68608];
    const int bid = (int)blockIdx.x;
    const int nbn = NVn * 8, nbs = NVs * 8;
    if (bid < nbn) {
        head_body(smem, bid, NVn, ctxh, ctxm, W_nrm, b_nrm, g_nrm, word_emb,
                  NWRDC, NWRDC + 1, tps_n, NWRDC / 128, nW, nBV, nBI, nE);
    } else if (bid < nbn + nbs) {
        head_body(smem, bid - nbn, NVs, ctxh, ctxm, W_spt, b_spt, g_spt,
                  word_emb_tgt, NTGTC, NTGTC, tps_s, (NTGTC + 127) / 128,
                  sW, sBV, sBI, sE);
    } else {
        cpy_body(smem, bid - nbn - nbs, ctxh, ctxm, ctxl, W_cpy, ctx, b_cpy,
                 pcpyP);
    }
}

// ---------------------------------------------------------------------------
__global__ __launch_bounds__(128) void combine_kernel(
    const int* __restrict__ inp_word, const float* __restrict__ masks,
    const int* __restrict__ spt_mask, const int* __restrict__ tgt_ids,
    const float* __restrict__ word_emb, const float* __restrict__ pcpyP,
    const float* __restrict__ g_nrm,
    const float* __restrict__ nW, const float* __restrict__ nBV,
    const int* __restrict__ nBI, const float* __restrict__ nE, int NVn,
    const float* __restrict__ sW, const float* __restrict__ sBV,
    const int* __restrict__ sBI, const float* __restrict__ sE, int NVs,
    float* __restrict__ out)
{
    const int t = (int)blockIdx.x;
    const int d = (int)threadIdx.x;

    float Wn = 0.f, En = 0.f, bv = -INFINITY; int bi = 0;
    for (int v = 0; v < NVn; ++v) {
        const size_t o = (size_t)v * TOK + t;
        Wn += nW[o];
        En += nE[o * DIM + d];
        const float vv = nBV[o]; const int ii = nBI[o];
        if (vv > bv || (vv == bv && ii < bi)) { bv = vv; bi = ii; }
    }
    float pc = 0.f;
    #pragma unroll
    for (int y = 0; y < 8; ++y) pc += pcpyP[(size_t)y * TOK + t];

    const int iw = inp_word[t];
    const float sc = pc + g_nrm[(size_t)t * (NWRDC + 1) + NWRDC];
    const float ec = __expf(sc);
    Wn += ec;
    En += ec * word_emb[(size_t)iw * DIM + d];
    const int ynrm = (sc > bv) ? iw : bi;

    float Ws = 0.f, Ese = 0.f, sv = -INFINITY; int si = 0;
    for (int v = 0; v < NVs; ++v) {
        const size_t o = (size_t)v * TOK + t;
        Ws += sW[o];
        Ese += sE[o * DIM + d];
        const float vv = sBV[o]; const int ii = sBI[o];
        if (vv > sv || (vv == sv && ii < si)) { sv = vv; si = ii; }
    }
    const int yspt = tgt_ids[si];

    const float sptf = (float)spt_mask[t];
    const float nrmf = (1.f - sptf) * masks[t];

    float eo; int obf;
    if (sptf > 0.f)      { eo = Ese / Ws; obf = yspt; }
    else if (nrmf > 0.f) { eo = En / Wn;  obf = ynrm; }
    else                 { obf = iw; eo = word_emb[(size_t)iw * DIM + d]; }

    out[(size_t)t * DIM + d] = eo;
    if (d == 0) {
        out[(size_t)TOK * DIM + t]       = (float)obf;
        out[(size_t)TOK * DIM + TOK + t] = sptf;
    }
}

// ---------------------------------------------------------------------------
extern "C" void kernel_launch(void* const* d_in, const int* in_sizes, int n_in,
                              void* d_out, int out_size, void* d_ws, size_t ws_size,
                              hipStream_t stream)
{
    const int*   inp_word = (const int*)d_in[0];
    const float* masks    = (const float*)d_in[1];
    const int*   spt_mask = (const int*)d_in[2];
    const int*   tgt_ids  = (const int*)d_in[3];
    const float* ctx      = (const float*)d_in[4];
    const float* W_spt    = (const float*)d_in[5];
    const float* b_spt    = (const float*)d_in[6];
    const float* W_nrm    = (const float*)d_in[7];
    const float* b_nrm    = (const float*)d_in[8];
    const float* W_cpy    = (const float*)d_in[9];
    const float* b_cpy    = (const float*)d_in[10];
    const float* word_emb = (const float*)d_in[11];
    const float* word_emb_tgt = (const float*)d_in[12];
    const float* g_spt    = (const float*)d_in[13];
    const float* g_nrm    = (const float*)d_in[14];
    float* out = (float*)d_out;

    char* wsb = (char*)d_ws;
    float*  pcpyP = (float*)wsb;                             // 32 KB
    ushort* ctxh = (ushort*)(wsb + 32768);                   // 2 MB
    ushort* ctxm = ctxh + 1048576;                           // 2 MB
    ushort* ctxl = ctxm + 1048576;                           // 2 MB
    char*   region = wsb + 32768 + 6291456;
    const size_t base = 32768 + 6291456;
    const size_t per_split = (size_t)TOK * (DIM + 3) * 4;    // 536576

    size_t navail = (ws_size > base + 2 * per_split)
                        ? (ws_size - base) / per_split : 2;
    int NVs = (int)(navail / 5);
    if (NVs < 1) NVs = 1; if (NVs > 8) NVs = 8;
    long rem = (long)navail - NVs;
    int NVn;
    if (rem >= 8) { NVn = (int)(rem & ~7L); if (NVn > 64) NVn = 64; }
    else          { NVn = (rem < 1) ? 1 : (int)rem; }

    float* nW  = (float*)region;
    float* nBV = nW + (size_t)NVn * TOK;
    int*   nBI = (int*)(nBV + (size_t)NVn * TOK);
    float* nE  = (float*)(nBI + (size_t)NVn * TOK);
    float* sW  = nE + (size_t)NVn * TOK * DIM;
    float* sBV = sW + (size_t)NVs * TOK;
    int*   sBI = (int*)(sBV + (size_t)NVs * TOK);
    float* sE  = (float*)(sBI + (size_t)NVs * TOK);

    const int tps_n = (NWRDC / 128 + NVn - 1) / NVn;
    const int ntile_s = (NTGTC + 127) / 128;
    const int tps_s = (ntile_s + NVs - 1) / NVs;

    split_ctx3<<<dim3(TOK * HSZ / 1024), dim3(256), 0, stream>>>(ctx, ctxh, ctxm, ctxl);
    mega_kernel<<<dim3(NVn * 8 + NVs * 8 + 64), dim3(256), 0, stream>>>(
        ctxh, ctxm, ctxl, W_nrm, b_nrm, g_nrm, word_emb,
        W_spt, b_spt, g_spt, word_emb_tgt, W_cpy, b_cpy, ctx, pcpyP,
        NVn, tps_n, NVs, tps_s, nW, nBV, nBI, nE, sW, sBV, sBI, sE);
    combine_kernel<<<dim3(TOK), dim3(128), 0, stream>>>(
        inp_word, masks, spt_mask, tgt_ids, word_emb, pcpyP, g_nrm,
        nW, nBV, nBI, nE, NVn, sW, sBV, sBI, sE, NVs, out);
    (void)in_sizes; (void)n_in; (void)out_size;
}